// Round 3
// baseline (99.788 us; speedup 1.0000x reference)
//
#include <hip/hip_runtime.h>
#include <hip/hip_bf16.h>

// ContrastiveLoss (NT-Xent): B=2048, D=256, T=0.5
// loss = mean_i [ -2*dot(zh_i, zh_pos(i)) + log( sum_j exp(2*dot(zh_i, zh_j)) - e^2 ) ]
// Symmetric Gram matrix: compute only upper-triangular 128x32 tiles; each
// off-diagonal-band tile contributes row sums AND column sums to S[4096].

typedef __attribute__((ext_vector_type(8))) short short8;
typedef __attribute__((ext_vector_type(4))) float float4v;

#define NROWS 4096
#define DIM 256
#define NB 2048
#define TEMP_INV 2.0f
// LDS row stride in shorts: 280 shorts = 140 dwords; each lane's b128 span
// (4 dwords) tiles the 32 banks at exactly 2 lanes/bank = conflict floor.
#define LDS_STRIDE 280
#define NTILES 2112  // sum_{ib=0}^{31} (128 - 4*ib)

static __device__ __forceinline__ unsigned short f2bf_rne(float f) {
    unsigned int x = __float_as_uint(f);
    unsigned int r = x + 0x7FFFu + ((x >> 16) & 1u);
    return (unsigned short)(r >> 16);
}
static __device__ __forceinline__ float bf2f(unsigned short u) {
    return __uint_as_float(((unsigned int)u) << 16);
}

// K1: L2-normalize rows of [z_i; z_j] -> zb (bf16). Zero S and d_out.
__global__ __launch_bounds__(256) void k_norm(const float* __restrict__ zi,
                                              const float* __restrict__ zj,
                                              unsigned short* __restrict__ zb,
                                              float* __restrict__ S,
                                              float* __restrict__ out) {
    if (blockIdx.x == 0 && threadIdx.x == 0) *out = 0.0f;
    if (threadIdx.x < 4) S[blockIdx.x * 4 + threadIdx.x] = 0.0f;
    int wave = threadIdx.x >> 6, lane = threadIdx.x & 63;
    int row = blockIdx.x * 4 + wave;
    const float* src = (row < NB) ? (zi + (size_t)row * DIM)
                                  : (zj + (size_t)(row - NB) * DIM);
    float4 v = *(const float4*)(src + lane * 4);
    float ss = v.x * v.x + v.y * v.y + v.z * v.z + v.w * v.w;
    #pragma unroll
    for (int off = 32; off > 0; off >>= 1) ss += __shfl_xor(ss, off);
    float scale = 1.0f / fmaxf(sqrtf(ss), 1e-12f);
    ushort4 pk;
    pk.x = f2bf_rne(v.x * scale); pk.y = f2bf_rne(v.y * scale);
    pk.z = f2bf_rne(v.z * scale); pk.w = f2bf_rne(v.w * scale);
    *(ushort4*)(zb + (size_t)row * DIM + lane * 4) = pk;
}

// K2: upper-triangular 128x32 exp-tiles. Block = 4 waves; wave owns 32 i-rows
// (two 16x16 A-tiles register-resident). B (32 j-rows) staged in LDS.
// Row sums for the tile's i-rows always; column sums for its j-cols when the
// tile is strictly above the 128-row diagonal band. All into S via atomics.
__global__ __launch_bounds__(256) void k_sim(const unsigned short* __restrict__ zb,
                                             float* __restrict__ S) {
    __shared__ __attribute__((aligned(16))) short Bs[32 * LDS_STRIDE];
    __shared__ float cs[32];
    // decode triangular tile index: iblk in [0,32), jc in [4*iblk, 128)
    int rem = blockIdx.x, iblk = 0;
    while (rem >= 128 - 4 * iblk) { rem -= 128 - 4 * iblk; iblk++; }
    int jc = 4 * iblk + rem;
    bool do_col = (jc >= 4 * iblk + 4);  // strictly above the diagonal band

    int tid = threadIdx.x, wave = tid >> 6, lane = tid & 63;
    int m = lane & 15, q = lane >> 4;
    const short* zs = (const short*)zb;
    int ibase = iblk * 128 + wave * 32;
    int j0 = jc * 32;

    if (tid < 32) cs[tid] = 0.0f;

    // stage B: 32 rows x 256 bf16 (16B chunks, 4 per thread)
    #pragma unroll
    for (int c = 0; c < 4; c++) {
        int chunk = c * 256 + tid;
        int r = chunk >> 5, cc = chunk & 31;
        *(short8*)(&Bs[r * LDS_STRIDE + cc * 8]) =
            *(const short8*)(zs + (size_t)(j0 + r) * DIM + cc * 8);
    }

    // A fragments: A[m][k], m = lane&15, k = q*8 + t  (verified 16x16x32 layout)
    short8 A[2][8];
    #pragma unroll
    for (int t = 0; t < 2; t++) {
        const short* arow = zs + (size_t)(ibase + t * 16 + m) * DIM + q * 8;
        #pragma unroll
        for (int kk = 0; kk < 8; kk++) A[t][kk] = *(const short8*)(arow + kk * 32);
    }
    __syncthreads();

    float rowacc[2][4] = {{0.f, 0.f, 0.f, 0.f}, {0.f, 0.f, 0.f, 0.f}};
    #pragma unroll
    for (int jt = 0; jt < 2; jt++) {
        const short* brow = &Bs[(jt * 16 + m) * LDS_STRIDE + q * 8];
        float4v c0 = {0.f, 0.f, 0.f, 0.f};
        float4v c1 = {0.f, 0.f, 0.f, 0.f};
        #pragma unroll
        for (int kk = 0; kk < 8; kk++) {
            short8 b = *(const short8*)(brow + kk * 32);
            c0 = __builtin_amdgcn_mfma_f32_16x16x32_bf16(A[0][kk], b, c0, 0, 0, 0);
            c1 = __builtin_amdgcn_mfma_f32_16x16x32_bf16(A[1][kk], b, c1, 0, 0, 0);
        }
        float csum = 0.0f;
        #pragma unroll
        for (int r = 0; r < 4; r++) {
            float e0 = __expf(TEMP_INV * c0[r]);
            float e1 = __expf(TEMP_INV * c1[r]);
            rowacc[0][r] += e0; rowacc[1][r] += e1;
            csum += e0 + e1;
        }
        if (do_col) {
            // column (j0 + jt*16 + m): sum this wave's 32 i-rows across q groups
            csum += __shfl_xor(csum, 16);
            csum += __shfl_xor(csum, 32);
            if (lane < 16) atomicAdd(&cs[jt * 16 + m], csum);
        }
    }

    // row sums: reduce over the 16 column-lanes, atomic to S
    #pragma unroll
    for (int t = 0; t < 2; t++) {
        #pragma unroll
        for (int r = 0; r < 4; r++) {
            float s = rowacc[t][r];
            s += __shfl_xor(s, 1);
            s += __shfl_xor(s, 2);
            s += __shfl_xor(s, 4);
            s += __shfl_xor(s, 8);
            if (m == 0) atomicAdd(&S[ibase + t * 16 + q * 4 + r], s);
        }
    }
    if (do_col) {
        __syncthreads();
        if (tid < 32) atomicAdd(&S[j0 + tid], cs[tid]);
    }
}

// K3: per-row loss terms from S + fp32 dot of bf16 rows. 128 blocks x 4 waves,
// 8 rows per wave, one atomicAdd per block.
__global__ __launch_bounds__(256) void k_loss(const unsigned short* __restrict__ zb,
                                              const float* __restrict__ S,
                                              float* __restrict__ out) {
    __shared__ float red[4];
    int wave = threadIdx.x >> 6, lane = threadIdx.x & 63;
    float wsum = 0.0f;
    #pragma unroll
    for (int t = 0; t < 8; t++) {
        int i = blockIdx.x * 32 + wave * 8 + t;
        int pos = (i + NB) & (NROWS - 1);
        ushort4 a = *(const ushort4*)(zb + (size_t)i * DIM + lane * 4);
        ushort4 b = *(const ushort4*)(zb + (size_t)pos * DIM + lane * 4);
        float d = bf2f(a.x) * bf2f(b.x) + bf2f(a.y) * bf2f(b.y) +
                  bf2f(a.z) * bf2f(b.z) + bf2f(a.w) * bf2f(b.w);
        #pragma unroll
        for (int off = 32; off > 0; off >>= 1) d += __shfl_xor(d, off);
        if (lane == 0) {
            const float E2 = 7.38905609893065f;  // exp(sim_ii) = e^2
            wsum += logf(S[i] - E2) - TEMP_INV * d;
        }
    }
    if (lane == 0) red[wave] = wsum;
    __syncthreads();
    if (threadIdx.x == 0) {
        float t = (red[0] + red[1] + red[2] + red[3]) * (1.0f / NROWS);
        atomicAdd(out, t);
    }
}

extern "C" void kernel_launch(void* const* d_in, const int* in_sizes, int n_in,
                              void* d_out, int out_size, void* d_ws, size_t ws_size,
                              hipStream_t stream) {
    const float* zi = (const float*)d_in[0];
    const float* zj = (const float*)d_in[1];
    float* out = (float*)d_out;
    char* ws = (char*)d_ws;
    unsigned short* zb = (unsigned short*)ws;        // 2 MB bf16 normalized rows
    float* S = (float*)(ws + 2 * 1024 * 1024);       // 16 KB per-row exp sums

    hipLaunchKernelGGL(k_norm, dim3(1024), dim3(256), 0, stream, zi, zj, zb, S, out);
    hipLaunchKernelGGL(k_sim, dim3(NTILES), dim3(256), 0, stream, zb, S);
    hipLaunchKernelGGL(k_loss, dim3(128), dim3(256), 0, stream, zb, S, out);
}

// Round 4
// 78.143 us; speedup vs baseline: 1.2770x; 1.2770x over previous
//
#include <hip/hip_runtime.h>
#include <hip/hip_bf16.h>

// ContrastiveLoss (NT-Xent): B=2048, D=256, T=0.5
// loss = mean_i [ -2*dot(zh_i, zh_pos(i)) + log( sum_j exp(2*dot(zh_i, zh_j)) - e^2 ) ]
// Symmetric Gram: only upper-triangular 128x128 tiles (528 blocks); each
// off-diagonal tile adds row sums AND column sums into S[4096] (atomics).
// A-side bf16 copy pre-scaled by 2*log2(e) so exp(2*sim) = exp2(dot) -> bare v_exp_f32.

typedef __attribute__((ext_vector_type(8))) short short8;
typedef __attribute__((ext_vector_type(4))) float float4v;

#define NROWS 4096
#define DIM 256
#define NB 2048
#define TEMP_INV 2.0f
#define SCALE 2.8853900817779268f  // 2*log2(e)
// LDS row stride in shorts: 280 = 140 dwords; each lane's b128 span tiles the
// 32 banks at exactly 2 lanes/bank = conflict floor (2-way free, m136).
#define LDS_STRIDE 280
#define NTILES 528  // 32*33/2 upper-triangular 128x128 tiles

static __device__ __forceinline__ unsigned short f2bf_rne(float f) {
    unsigned int x = __float_as_uint(f);
    unsigned int r = x + 0x7FFFu + ((x >> 16) & 1u);
    return (unsigned short)(r >> 16);
}

// K1: normalize pair (p, p+NB); write zb (bf16), zb2 (bf16 * 2log2e), pos-dot pd[p].
// Also zero S and out. grid 512 x 256.
__global__ __launch_bounds__(256) void k_norm(const float* __restrict__ zi,
                                              const float* __restrict__ zj,
                                              unsigned short* __restrict__ zb,
                                              unsigned short* __restrict__ zb2,
                                              float* __restrict__ pd,
                                              float* __restrict__ S,
                                              float* __restrict__ out) {
    if (blockIdx.x == 0 && threadIdx.x == 0) *out = 0.0f;
    if (threadIdx.x < 8) S[blockIdx.x * 8 + threadIdx.x] = 0.0f;
    int wave = threadIdx.x >> 6, lane = threadIdx.x & 63;
    int p = blockIdx.x * 4 + wave;  // pair index, rows p and p+NB
    float4 vi = *(const float4*)(zi + (size_t)p * DIM + lane * 4);
    float4 vj = *(const float4*)(zj + (size_t)p * DIM + lane * 4);
    float ssi = vi.x * vi.x + vi.y * vi.y + vi.z * vi.z + vi.w * vi.w;
    float ssj = vj.x * vj.x + vj.y * vj.y + vj.z * vj.z + vj.w * vj.w;
    float dij = vi.x * vj.x + vi.y * vj.y + vi.z * vj.z + vi.w * vj.w;
    #pragma unroll
    for (int off = 32; off > 0; off >>= 1) {
        ssi += __shfl_xor(ssi, off);
        ssj += __shfl_xor(ssj, off);
        dij += __shfl_xor(dij, off);
    }
    float si = 1.0f / fmaxf(sqrtf(ssi), 1e-12f);
    float sj = 1.0f / fmaxf(sqrtf(ssj), 1e-12f);
    ushort4 a, b;
    a.x = f2bf_rne(vi.x * si); a.y = f2bf_rne(vi.y * si);
    a.z = f2bf_rne(vi.z * si); a.w = f2bf_rne(vi.w * si);
    b.x = f2bf_rne(vj.x * sj); b.y = f2bf_rne(vj.y * sj);
    b.z = f2bf_rne(vj.z * sj); b.w = f2bf_rne(vj.w * sj);
    *(ushort4*)(zb + (size_t)p * DIM + lane * 4) = a;
    *(ushort4*)(zb + (size_t)(p + NB) * DIM + lane * 4) = b;
    float ki = si * SCALE, kj = sj * SCALE;
    ushort4 a2, b2;
    a2.x = f2bf_rne(vi.x * ki); a2.y = f2bf_rne(vi.y * ki);
    a2.z = f2bf_rne(vi.z * ki); a2.w = f2bf_rne(vi.w * ki);
    b2.x = f2bf_rne(vj.x * kj); b2.y = f2bf_rne(vj.y * kj);
    b2.z = f2bf_rne(vj.z * kj); b2.w = f2bf_rne(vj.w * kj);
    *(ushort4*)(zb2 + (size_t)p * DIM + lane * 4) = a2;
    *(ushort4*)(zb2 + (size_t)(p + NB) * DIM + lane * 4) = b2;
    if (lane == 0) pd[p] = dij * si * sj;
}

// K2: upper-triangular 128x128 exp2-tiles. Block = 4 waves; wave owns 32 i-rows
// (two 16x16 A-tiles register-resident from zb2). B strips (64 rows of zb) in LDS.
// Row sums always; col sums (via LDS cs[128]) when jb > ib. Atomics into S.
__global__ __launch_bounds__(256) void k_sim(const unsigned short* __restrict__ zb,
                                             const unsigned short* __restrict__ zb2,
                                             float* __restrict__ S) {
    __shared__ __attribute__((aligned(16))) short Bs[64 * LDS_STRIDE];
    __shared__ float cs[128];
    // decode triangular tile: ib in [0,32), jb in [ib,32)
    int rem = blockIdx.x, ib = 0;
    while (rem >= 32 - ib) { rem -= 32 - ib; ib++; }
    int jb = ib + rem;
    bool do_col = (jb > ib);

    int tid = threadIdx.x, wave = tid >> 6, lane = tid & 63;
    int m = lane & 15, q = lane >> 4;
    const short* zsB = (const short*)zb;
    const short* zsA = (const short*)zb2;
    int ibase = ib * 128 + wave * 32;
    int jtile0 = jb * 128;

    if (tid < 128) cs[tid] = 0.0f;

    // A fragments: A[m][k], m = lane&15, k = q*8 + t  (verified 16x16x32 layout)
    short8 A[2][8];
    #pragma unroll
    for (int t = 0; t < 2; t++) {
        const short* arow = zsA + (size_t)(ibase + t * 16 + m) * DIM + q * 8;
        #pragma unroll
        for (int kk = 0; kk < 8; kk++) A[t][kk] = *(const short8*)(arow + kk * 32);
    }

    float rowacc[2][4] = {{0.f, 0.f, 0.f, 0.f}, {0.f, 0.f, 0.f, 0.f}};

    #pragma unroll
    for (int strip = 0; strip < 2; strip++) {
        int j0 = jtile0 + strip * 64;
        __syncthreads();
        // stage 64 B-rows x 256 bf16 into LDS
        #pragma unroll
        for (int c = 0; c < 8; c++) {
            int chunk = c * 256 + tid;          // 16B chunks
            int r = chunk >> 5, cc = chunk & 31;
            *(short8*)(&Bs[r * LDS_STRIDE + cc * 8]) =
                *(const short8*)(zsB + (size_t)(j0 + r) * DIM + cc * 8);
        }
        __syncthreads();

        #pragma unroll
        for (int jt = 0; jt < 4; jt++) {
            const short* brow = &Bs[(jt * 16 + m) * LDS_STRIDE + q * 8];
            float4v c0 = {0.f, 0.f, 0.f, 0.f};
            float4v c1 = {0.f, 0.f, 0.f, 0.f};
            #pragma unroll
            for (int kk = 0; kk < 8; kk++) {
                short8 b = *(const short8*)(brow + kk * 32);
                c0 = __builtin_amdgcn_mfma_f32_16x16x32_bf16(A[0][kk], b, c0, 0, 0, 0);
                c1 = __builtin_amdgcn_mfma_f32_16x16x32_bf16(A[1][kk], b, c1, 0, 0, 0);
            }
            float csum = 0.0f;
            #pragma unroll
            for (int r = 0; r < 4; r++) {
                float e0 = __builtin_exp2f(c0[r]);
                float e1 = __builtin_exp2f(c1[r]);
                rowacc[0][r] += e0; rowacc[1][r] += e1;
                csum += e0 + e1;
            }
            if (do_col) {
                // column strip*64 + jt*16 + m: sum over this wave's 32 rows
                csum += __shfl_xor(csum, 16);
                csum += __shfl_xor(csum, 32);
                if (lane < 16) atomicAdd(&cs[strip * 64 + jt * 16 + m], csum);
            }
        }
    }

    // row sums: reduce over 16 column-lanes, atomic into S
    #pragma unroll
    for (int t = 0; t < 2; t++) {
        #pragma unroll
        for (int r = 0; r < 4; r++) {
            float s = rowacc[t][r];
            s += __shfl_xor(s, 1);
            s += __shfl_xor(s, 2);
            s += __shfl_xor(s, 4);
            s += __shfl_xor(s, 8);
            if (m == 0) atomicAdd(&S[ibase + t * 16 + q * 4 + r], s);
        }
    }
    if (do_col) {
        __syncthreads();
        if (tid < 128) atomicAdd(&S[jtile0 + tid], cs[tid]);
    }
}

// K3: loss = mean over rows of log(S[i]-e^2) - 2*pd[i%NB]. grid 16 x 256.
__global__ __launch_bounds__(256) void k_loss(const float* __restrict__ S,
                                              const float* __restrict__ pd,
                                              float* __restrict__ out) {
    __shared__ float red[4];
    int wave = threadIdx.x >> 6, lane = threadIdx.x & 63;
    int i = blockIdx.x * 256 + threadIdx.x;
    const float E2 = 7.38905609893065f;  // exp(sim_ii) = e^2
    float term = logf(S[i] - E2) - TEMP_INV * pd[i & (NB - 1)];
    #pragma unroll
    for (int off = 32; off > 0; off >>= 1) term += __shfl_xor(term, off);
    if (lane == 0) red[wave] = term;
    __syncthreads();
    if (threadIdx.x == 0) {
        float t = (red[0] + red[1] + red[2] + red[3]) * (1.0f / NROWS);
        atomicAdd(out, t);
    }
}

extern "C" void kernel_launch(void* const* d_in, const int* in_sizes, int n_in,
                              void* d_out, int out_size, void* d_ws, size_t ws_size,
                              hipStream_t stream) {
    const float* zi = (const float*)d_in[0];
    const float* zj = (const float*)d_in[1];
    float* out = (float*)d_out;
    char* ws = (char*)d_ws;
    unsigned short* zb  = (unsigned short*)ws;                        // 2 MB bf16 normalized
    unsigned short* zb2 = (unsigned short*)(ws + 2 * 1024 * 1024);    // 2 MB bf16 * 2log2e
    float* S  = (float*)(ws + 4 * 1024 * 1024);                       // 16 KB row exp sums
    float* pd = (float*)(ws + 4 * 1024 * 1024 + 16 * 1024);           // 8 KB pos dots

    hipLaunchKernelGGL(k_norm, dim3(512), dim3(256), 0, stream, zi, zj, zb, zb2, pd, S, out);
    hipLaunchKernelGGL(k_sim, dim3(NTILES), dim3(256), 0, stream, zb, zb2, S);
    hipLaunchKernelGGL(k_loss, dim3(16), dim3(256), 0, stream, S, pd, out);
}